// Round 10
// baseline (7018.194 us; speedup 1.0000x reference)
//
#include <hip/hip_runtime.h>
#include <math.h>

// Seq2seq LSTM: 5-layer stack, HID=80, 336 enc + 48 dec steps, batch 512.
// R10: R9 wavefront + fully software-pipelined inner loops:
//   - encoder: manual A/B ping-pong (no reg copies), h ds_reads AND weight
//     loads prefetched one chunk ahead (R9 stalled ~120cy/iter on ds_read)
//   - weights repacked j-contiguous (64B/lane from one base: imm offsets)
//   - decoder: R9 copy-style depth-1 + h prefetch
#define LAYERS  5
#define HID     80
#define GATES   320
#define INDIM   4
#define BATCH   512
#define SEQLEN  336
#define PREDLEN 48
#define TOT     (SEQLEN + PREDLEN)
#define NB      4
#define NTHR    800
#define NSUP    (SEQLEN + LAYERS - 1)   // 340 supersteps

// h-buffer strides: per-batch 96 (80 h + 4 x-slot + pad), per-layer 384
#define BSTR 96
#define LSTR 384
#define HTOT (LAYERS * LSTR)            // 1920 floats per parity buffer

// ws (float4 units): [enc 64000][dec 64000][enc bias 400][dec bias 400]
//  enc: idx ((wl*20 + i)*160 + lt)*4 + j   lt=m*2+mat, row=m+80j
//       l>0: mat0=Whh[l][row][4i], mat1=Wih[l-1][row][4i]
//       l=0: mat0: i<10 ? Whh0[row][4i] : 0
//            mat1: i<10 ? Whh0[row][40+4i] : (i==10 ? W0[row][0:4] : 0)
//  dec: idx ((5l+i)*640 + tid)*4 + j       tid=(m,mat,kq), k0=kq*20+4i
//       l=0: mat0=Whh0[row][k0]; mat1=(kq==0&&i==0)?W0[row]:0
//       l>0: mat0=Whh[l][row][k0]; mat1=Wih[l-1][row][k0]
#define NE4    64000
#define ND4    64000
#define OFF_D  NE4
#define OFF_BE (NE4 + ND4)
#define OFF_BD (OFF_BE + 400)
#define NWS4   (OFF_BD + 400)
#define WS_NEED ((size_t)NWS4 * 16)
#define NPREP  (NE4 + ND4 + 800)

__device__ __forceinline__ float sigm(float v) { return 1.0f / (1.0f + __expf(-v)); }
__device__ __forceinline__ float tanh_fast(float v) {
    return 1.0f - 2.0f / (1.0f + __expf(2.0f * v));
}
__device__ __forceinline__ float gate_act(float v, bool tg) {
    const float e = __expf(tg ? 2.0f * v : -v);
    const float r = 1.0f / (1.0f + e);
    return tg ? 1.0f - 2.0f * r : r;
}
__device__ __forceinline__ float rs4(float v0, float v1, float v2, float v3, int q) {
    float u = (q & 1) ? v1 : v0;
    float s = (q & 1) ? v0 : v1;
    u += __shfl_xor(s, 1);
    float u2 = (q & 1) ? v3 : v2;
    float s2 = (q & 1) ? v2 : v3;
    u2 += __shfl_xor(s2, 1);
    float k = (q & 2) ? u2 : u;
    float s3 = (q & 2) ? u : u2;
    k += __shfl_xor(s3, 2);
    return k;
}

// 16 float4-FMAs: weight set W[4] (gates) x h set H[4] (batches) into a[4][4]
#define FMA16(W, H)                                                              \
    do {                                                                         \
        _Pragma("unroll")                                                        \
        for (int _j = 0; _j < 4; ++_j) {                                         \
            _Pragma("unroll")                                                    \
            for (int _b = 0; _b < 4; ++_b)                                       \
                a[_j][_b] += (W)[_j].x * (H)[_b].x + (W)[_j].y * (H)[_b].y       \
                           + (W)[_j].z * (H)[_b].z + (W)[_j].w * (H)[_b].w;      \
        }                                                                        \
    } while (0)

// ================= prep: pack weights/biases =================
__global__ void prep_pack(const float* __restrict__ eW0,  const float* __restrict__ eWih,
                          const float* __restrict__ eWhh, const float* __restrict__ ebih,
                          const float* __restrict__ ebhh,
                          const float* __restrict__ dW0,  const float* __restrict__ dWih,
                          const float* __restrict__ dWhh, const float* __restrict__ dbih,
                          const float* __restrict__ dbhh, float* __restrict__ ws)
{
    const int gid = blockIdx.x * 256 + threadIdx.x;
    float4* w4 = (float4*)ws;
    if (gid < NE4) {                    // encoder: ((wl*20+i)*160+lt)*4 + j
        const int j  = gid & 3;
        const int r  = gid >> 2;
        const int lt = r % 160;
        const int i  = (r / 160) % 20;
        const int l  = r / 3200;
        const int m = lt >> 1, mat = lt & 1;
        const int row = m + 80 * j;
        float4 v = make_float4(0.f, 0.f, 0.f, 0.f);
        if (l > 0) {
            v = mat ? *(const float4*)&eWih[((size_t)(l - 1) * GATES + row) * HID + 4 * i]
                    : *(const float4*)&eWhh[((size_t)l * GATES + row) * HID + 4 * i];
        } else if (!mat) {
            if (i < 10) v = *(const float4*)&eWhh[(size_t)row * HID + 4 * i];
        } else {
            if (i < 10)       v = *(const float4*)&eWhh[(size_t)row * HID + 40 + 4 * i];
            else if (i == 10) v = *(const float4*)&eW0[row * INDIM];
        }
        w4[gid] = v;
        return;
    }
    int g2 = gid - NE4;
    if (g2 < ND4) {                     // decoder: ((5l+i)*640+tid)*4 + j
        const int j    = g2 & 3;
        const int r    = g2 >> 2;
        const int tid  = r % 640;
        const int slot = r / 640;       // 0..24
        const int l = slot / 5, i = slot % 5;
        const int m = tid >> 3, mat = (tid >> 2) & 1, kq = tid & 3;
        const int row = m + 80 * j;
        const int k0 = kq * 20 + 4 * i;
        float4 v = make_float4(0.f, 0.f, 0.f, 0.f);
        if (l == 0) {
            if (!mat)                    v = *(const float4*)&dWhh[(size_t)row * HID + k0];
            else if (kq == 0 && i == 0)  v = *(const float4*)&dW0[row * INDIM];
        } else {
            v = mat ? *(const float4*)&dWih[((size_t)(l - 1) * GATES + row) * HID + k0]
                    : *(const float4*)&dWhh[((size_t)l * GATES + row) * HID + k0];
        }
        w4[OFF_D + g2] = v;
        return;
    }
    int g3 = g2 - ND4;
    if (g3 < 800) {                     // biases: [ctx][l][m] f4 over gates
        const int ctx = g3 / 400, r = g3 % 400;
        const int l = r / 80, m = r % 80;
        const float* bi = ctx ? dbih : ebih;
        const float* bh = ctx ? dbhh : ebhh;
        float4 v;
        v.x = bi[l * GATES + m]       + bh[l * GATES + m];
        v.y = bi[l * GATES + m + 80]  + bh[l * GATES + m + 80];
        v.z = bi[l * GATES + m + 160] + bh[l * GATES + m + 160];
        v.w = bi[l * GATES + m + 240] + bh[l * GATES + m + 240];
        w4[OFF_BE + g3] = v;
    }
}

// ================= main persistent kernel =================
__global__ __launch_bounds__(NTHR) void lstm_main(
    const float* __restrict__ x,   const float* __restrict__ ff,
    const float* __restrict__ fcW, const float* __restrict__ fcb,
    const float* __restrict__ ws,  float* __restrict__ out)
{
    __shared__ __align__(16) float hA[HTOT];     // parity-0 h (+x slots)
    __shared__ __align__(16) float hB[HTOT];     // parity-1 h
    __shared__ __align__(16) float cS[LAYERS * NB * HID];
    __shared__ __align__(16) float sx[NB][20];   // decoder input (zero-padded)

    const float4* w4  = (const float4*)ws;
    const float4* w4d = w4 + OFF_D;
    const float4* b4e = w4 + OFF_BE;
    const float4* b4d = w4 + OFF_BD;

    const int tid = threadIdx.x;
    const int b0  = blockIdx.x * NB;

    for (int i = tid; i < HTOT; i += NTHR) { hA[i] = 0.0f; hB[i] = 0.0f; }
    for (int i = tid; i < LAYERS * NB * HID; i += NTHR) cS[i] = 0.0f;
    if (tid < NB * 20) ((float*)sx)[tid] = 0.0f;
    if (tid < NB)      // prestage x(0) into hB x-slots (prv of superstep 0)
        *(float4*)&hB[tid * BSTR + 80] = *(const float4*)&x[((size_t)(b0 + tid) * SEQLEN) * INDIM];
    __syncthreads();

    // ---------------- encoder: wavefront supersteps ----------------
    const int wl   = tid / 160;          // layer worker
    const int lt   = tid % 160;
    const int em   = lt >> 1;            // unit
    const int emat = lt & 1;             // matrix half

    #pragma unroll 1
    for (int s = 0; s < NSUP; ++s) {
        float* cur = (s & 1) ? hB : hA;
        float* prv = (s & 1) ? hA : hB;
        const int t = s - wl;

        if (tid < NB && s + 1 < SEQLEN)  // stage x(s+1) into cur x-slot
            *(float4*)&cur[tid * BSTR + 80] =
                *(const float4*)&x[((size_t)(b0 + tid) * SEQLEN + (s + 1)) * INDIM];

        if (t >= 0 && t < SEQLEN) {
            const float* hbase = emat ? (wl ? prv + (wl - 1) * LSTR : prv + 40)
                                      : prv + wl * LSTR;
            const float4* wp = w4 + (size_t)wl * 12800 + 4 * lt;

            // ping-pong register sets A (even chunks) / B (odd chunks)
            float4 wA[4], wB[4], hAr[4], hBr[4];
            wA[0] = wp[0];   wA[1] = wp[1];   wA[2] = wp[2];   wA[3] = wp[3];
            wB[0] = wp[640]; wB[1] = wp[641]; wB[2] = wp[642]; wB[3] = wp[643];
            hAr[0] = *(const float4*)(hbase + 0 * BSTR);
            hAr[1] = *(const float4*)(hbase + 1 * BSTR);
            hAr[2] = *(const float4*)(hbase + 2 * BSTR);
            hAr[3] = *(const float4*)(hbase + 3 * BSTR);
            hBr[0] = *(const float4*)(hbase + 0 * BSTR + 4);
            hBr[1] = *(const float4*)(hbase + 1 * BSTR + 4);
            hBr[2] = *(const float4*)(hbase + 2 * BSTR + 4);
            hBr[3] = *(const float4*)(hbase + 3 * BSTR + 4);

            float a[4][4];
            #pragma unroll
            for (int j = 0; j < 4; ++j)
                #pragma unroll
                for (int b = 0; b < 4; ++b) a[j][b] = 0.0f;

            #pragma unroll 1
            for (int ii = 0; ii < 9; ++ii) {     // chunks 2ii, 2ii+1; load +2,+3
                const int ho = 8 * ii + 8;
                FMA16(wA, hAr);
                wA[0] = wp[1280]; wA[1] = wp[1281]; wA[2] = wp[1282]; wA[3] = wp[1283];
                hAr[0] = *(const float4*)(hbase + 0 * BSTR + ho);
                hAr[1] = *(const float4*)(hbase + 1 * BSTR + ho);
                hAr[2] = *(const float4*)(hbase + 2 * BSTR + ho);
                hAr[3] = *(const float4*)(hbase + 3 * BSTR + ho);
                FMA16(wB, hBr);
                wB[0] = wp[1920]; wB[1] = wp[1921]; wB[2] = wp[1922]; wB[3] = wp[1923];
                hBr[0] = *(const float4*)(hbase + 0 * BSTR + ho + 4);
                hBr[1] = *(const float4*)(hbase + 1 * BSTR + ho + 4);
                hBr[2] = *(const float4*)(hbase + 2 * BSTR + ho + 4);
                hBr[3] = *(const float4*)(hbase + 3 * BSTR + ho + 4);
                wp += 1280;
            }
            FMA16(wA, hAr);                      // chunk 18
            FMA16(wB, hBr);                      // chunk 19

            // 2-lane fold: lane keeps batches {2*emat, 2*emat+1}
            float sA[4], sB[4];
            #pragma unroll
            for (int j = 0; j < 4; ++j) {
                float u0 = emat ? a[j][0] : a[j][2];
                float r0 = __shfl_xor(u0, 1);
                sA[j] = (emat ? a[j][2] : a[j][0]) + r0;
                float u1 = emat ? a[j][1] : a[j][3];
                float r1 = __shfl_xor(u1, 1);
                sB[j] = (emat ? a[j][3] : a[j][1]) + r1;
            }

            const float4 bv = b4e[wl * 80 + em];
            const int blo = 2 * emat;
            {   // batch blo
                const float gi = sigm(sA[0] + bv.x);
                const float gf = sigm(sA[1] + bv.y);
                const float gg = tanh_fast(sA[2] + bv.z);
                const float go = sigm(sA[3] + bv.w);
                const int ci = wl * 320 + blo * 80 + em;
                const float cn = gf * cS[ci] + gi * gg;
                cS[ci] = cn;
                cur[wl * LSTR + blo * BSTR + em] = go * tanh_fast(cn);
            }
            {   // batch blo+1
                const float gi = sigm(sB[0] + bv.x);
                const float gf = sigm(sB[1] + bv.y);
                const float gg = tanh_fast(sB[2] + bv.z);
                const float go = sigm(sB[3] + bv.w);
                const int ci = wl * 320 + (blo + 1) * 80 + em;
                const float cn = gf * cS[ci] + gi * gg;
                cS[ci] = cn;
                cur[wl * LSTR + (blo + 1) * BSTR + em] = go * tanh_fast(cn);
            }
        }
        __syncthreads();
    }

    // ---------------- transition: gather final h into hB; stage dec input ----
    // h_l(335) lives in buf[(335+l)&1]: layers 1,3 are in hA -> copy to hB.
    for (int i = tid; i < 2 * LSTR; i += NTHR) {
        const int l = (i < LSTR) ? 1 : 3;
        const int off = i % LSTR;
        hB[l * LSTR + off] = hA[l * LSTR + off];
    }
    if (tid < NB * INDIM)
        sx[tid >> 2][tid & 3] =
            x[((size_t)(b0 + (tid >> 2)) * SEQLEN + (SEQLEN - 1)) * INDIM + (tid & 3)];
    __syncthreads();

    // ---------------- decoder: R8 mapping on 640 threads ----------------
    const int dm   = tid >> 3;
    const int dmat = (tid >> 2) & 1;
    const int dkq  = tid & 3;

    #pragma unroll 1
    for (int t = SEQLEN; t < TOT; ++t) {
        float* cur = (t & 1) ? hB : hA;
        float* prv = (t & 1) ? hA : hB;

        #pragma unroll 1
        for (int l = 0; l < LAYERS; ++l) {
            if (tid < 640) {
                const float* hb0;
                int hstr;
                if (l == 0) {
                    if (dmat) { hb0 = &sx[0][0];        hstr = 20;   }
                    else      { hb0 = prv + dkq * 20;   hstr = BSTR; }
                } else {
                    hb0 = (dmat ? (cur + (l - 1) * LSTR) : (prv + l * LSTR)) + dkq * 20;
                    hstr = BSTR;
                }
                const float* hb1 = hb0 + hstr;
                const float* hb2 = hb1 + hstr;
                const float* hb3 = hb2 + hstr;

                const float4* wp = w4d + (size_t)(5 * l) * 2560 + 4 * tid;
                float4 wv[4], hv[4];
                wv[0] = wp[0]; wv[1] = wp[1]; wv[2] = wp[2]; wv[3] = wp[3];
                hv[0] = *(const float4*)(hb0);
                hv[1] = *(const float4*)(hb1);
                hv[2] = *(const float4*)(hb2);
                hv[3] = *(const float4*)(hb3);

                float a[4][4];
                #pragma unroll
                for (int j = 0; j < 4; ++j)
                    #pragma unroll
                    for (int b = 0; b < 4; ++b) a[j][b] = 0.0f;

                #pragma unroll 1
                for (int i = 0; i < 4; ++i) {
                    const float4* np = wp + 2560;
                    float4 nv[4], hn[4];
                    nv[0] = np[0]; nv[1] = np[1]; nv[2] = np[2]; nv[3] = np[3];
                    hn[0] = *(const float4*)(hb0 + 4 * i + 4);
                    hn[1] = *(const float4*)(hb1 + 4 * i + 4);
                    hn[2] = *(const float4*)(hb2 + 4 * i + 4);
                    hn[3] = *(const float4*)(hb3 + 4 * i + 4);
                    FMA16(wv, hv);
                    #pragma unroll
                    for (int j = 0; j < 4; ++j) { wv[j] = nv[j]; hv[j] = hn[j]; }
                    wp = np;
                }
                FMA16(wv, hv);                   // chunk 4

                float s[4];
                #pragma unroll
                for (int j = 0; j < 4; ++j)
                    s[j] = rs4(a[j][0], a[j][1], a[j][2], a[j][3], dkq);
                #pragma unroll
                for (int j = 0; j < 4; ++j)
                    s[j] += __shfl_xor(s[j], 4);

                const float4 bv = b4d[l * 80 + dm];
                float act0, act1;
                if (!dmat) { act0 = sigm(s[0] + bv.x);      act1 = sigm(s[1] + bv.y); }
                else       { act0 = tanh_fast(s[2] + bv.z); act1 = sigm(s[3] + bv.w); }
                const float o0 = __shfl_xor(act0, 4);
                const float o1 = __shfl_xor(act1, 4);
                const float gi = dmat ? o0 : act0;
                const float gf = dmat ? o1 : act1;
                const float gg = dmat ? act0 : o0;
                const float go = dmat ? act1 : o1;

                if (!dmat) {
                    const int ci = l * 320 + dkq * 80 + dm;
                    const float cn = gf * cS[ci] + gi * gg;
                    cS[ci] = cn;
                    cur[l * LSTR + dkq * BSTR + dm] = go * tanh_fast(cn);
                }
            }
            __syncthreads();
        }

        const int td = t - SEQLEN;
        if (tid < NB) {                 // pred + feedback
            float s = fcb[0];
            const float* hvp = cur + 4 * LSTR + tid * BSTR;
            #pragma unroll
            for (int jj = 0; jj < HID; jj += 4) {
                const float4 wv4 = *(const float4*)&fcW[jj];
                const float4 h4  = *(const float4*)&hvp[jj];
                s += wv4.x * h4.x + wv4.y * h4.y + wv4.z * h4.z + wv4.w * h4.w;
            }
            out[(size_t)(b0 + tid) * PREDLEN + td] = s;
            sx[tid][0] = s;
        } else if (tid >= 64 && tid < 64 + NB * 3) {
            const int qd = tid - 64;
            const int nb = qd / 3, k = qd % 3;
            sx[nb][k + 1] = ff[((size_t)(b0 + nb) * PREDLEN + td) * 3 + k];
        }
        __syncthreads();
    }
}

// ================= fallback (R5 kernel, proven) if ws too small =================
#define FQK 20
#define FCHUNK(WPTR, HPTR, I)                                                    \
    do {                                                                         \
        const float4 wA = *(const float4*)((WPTR) + 4 * (I));                    \
        const float4 wB = *(const float4*)((WPTR) + HID + 4 * (I));              \
        const float* _hb = (HPTR);                                               \
        const float4 h0 = *(const float4*)(_hb + 0 * HID + 4 * (I));             \
        const float4 h1 = *(const float4*)(_hb + 1 * HID + 4 * (I));             \
        const float4 h2 = *(const float4*)(_hb + 2 * HID + 4 * (I));             \
        const float4 h3 = *(const float4*)(_hb + 3 * HID + 4 * (I));             \
        a00 += wA.x * h0.x + wA.y * h0.y + wA.z * h0.z + wA.w * h0.w;            \
        a01 += wA.x * h1.x + wA.y * h1.y + wA.z * h1.z + wA.w * h1.w;            \
        a02 += wA.x * h2.x + wA.y * h2.y + wA.z * h2.z + wA.w * h2.w;            \
        a03 += wA.x * h3.x + wA.y * h3.y + wA.z * h3.z + wA.w * h3.w;            \
        a10 += wB.x * h0.x + wB.y * h0.y + wB.z * h0.z + wB.w * h0.w;            \
        a11 += wB.x * h1.x + wB.y * h1.y + wB.z * h1.z + wB.w * h1.w;            \
        a12 += wB.x * h2.x + wB.y * h2.y + wB.z * h2.z + wB.w * h2.w;            \
        a13 += wB.x * h3.x + wB.y * h3.y + wB.z * h3.z + wB.w * h3.w;            \
    } while (0)

__global__ __launch_bounds__(640) void lstm_fb(
    const float* __restrict__ x,    const float* __restrict__ ff,
    const float* __restrict__ eW0,  const float* __restrict__ eWih,
    const float* __restrict__ eWhh, const float* __restrict__ ebih,
    const float* __restrict__ ebhh,
    const float* __restrict__ dW0,  const float* __restrict__ dWih,
    const float* __restrict__ dWhh, const float* __restrict__ dbih,
    const float* __restrict__ dbhh,
    const float* __restrict__ fcW,  const float* __restrict__ fcb,
    float* __restrict__ out)
{
    __shared__ __align__(16) float sh[LAYERS][NB][HID];
    __shared__ __align__(16) float sc[LAYERS][NB][HID];
    __shared__ __align__(16) float sg[NB][GATES + 1];
    __shared__ __align__(16) float sx[NB][INDIM];

    const int tid = threadIdx.x;
    const int q   = tid & 3;
    const int mm  = tid >> 2;
    const int r0  = 2 * mm;
    const int b0  = blockIdx.x * NB;

    for (int i = tid; i < LAYERS * NB * HID; i += 640) {
        (&sh[0][0][0])[i] = 0.0f;
        (&sc[0][0][0])[i] = 0.0f;
    }
    const bool is_tg = (r0 >= 2 * HID) && (r0 < 3 * HID);
    const int  unb = tid / HID, uj = tid % HID;

    float bs[2][LAYERS][2];
    #pragma unroll
    for (int l = 0; l < LAYERS; ++l) {
        bs[0][l][0] = ebih[l * GATES + r0]     + ebhh[l * GATES + r0];
        bs[0][l][1] = ebih[l * GATES + r0 + 1] + ebhh[l * GATES + r0 + 1];
        bs[1][l][0] = dbih[l * GATES + r0]     + dbhh[l * GATES + r0];
        bs[1][l][1] = dbih[l * GATES + r0 + 1] + dbhh[l * GATES + r0 + 1];
    }
    const float w0e0 = eW0[r0 * INDIM + q], w0e1 = eW0[(r0 + 1) * INDIM + q];
    const float w0d0 = dW0[r0 * INDIM + q], w0d1 = dW0[(r0 + 1) * INDIM + q];

    for (int t = 0; t < TOT; ++t) {
        const bool enc = (t < SEQLEN);
        const float* Wih = enc ? eWih : dWih;
        const float* Whh = enc ? eWhh : dWhh;
        if (enc && tid < NB * INDIM) {
            const int nb = tid / INDIM, k = tid % INDIM;
            sx[nb][k] = x[((size_t)(b0 + nb) * SEQLEN + t) * INDIM + k];
        }
        __syncthreads();
        #pragma unroll
        for (int l = 0; l < LAYERS; ++l) {
            float a00 = 0.f, a01 = 0.f, a02 = 0.f, a03 = 0.f;
            float a10 = 0.f, a11 = 0.f, a12 = 0.f, a13 = 0.f;
            {
                const float* wp = Whh + ((size_t)l * GATES + r0) * HID + q * FQK;
                const float* hp = &sh[l][0][q * FQK];
                #pragma unroll
                for (int i = 0; i < FQK / 4; ++i) FCHUNK(wp, hp, i);
            }
            if (l == 0) {
                const float wa = enc ? w0e0 : w0d0;
                const float wb = enc ? w0e1 : w0d1;
                a00 += wa * sx[0][q];  a01 += wa * sx[1][q];
                a02 += wa * sx[2][q];  a03 += wa * sx[3][q];
                a10 += wb * sx[0][q];  a11 += wb * sx[1][q];
                a12 += wb * sx[2][q];  a13 += wb * sx[3][q];
            } else {
                const float* wp = Wih + ((size_t)(l - 1) * GATES + r0) * HID + q * FQK;
                const float* hp = &sh[l - 1][0][q * FQK];
                #pragma unroll
                for (int i = 0; i < FQK / 4; ++i) FCHUNK(wp, hp, i);
            }
            const float s0 = rs4(a00, a01, a02, a03, q);
            const float s1 = rs4(a10, a11, a12, a13, q);
            const float bias0 = enc ? bs[0][l][0] : bs[1][l][0];
            const float bias1 = enc ? bs[0][l][1] : bs[1][l][1];
            sg[q][r0]     = gate_act(s0 + bias0, is_tg);
            sg[q][r0 + 1] = gate_act(s1 + bias1, is_tg);
            __syncthreads();
            if (tid < NB * HID) {
                const float iv = sg[unb][uj];
                const float fv = sg[unb][uj + HID];
                const float gv = sg[unb][uj + 2 * HID];
                const float ov = sg[unb][uj + 3 * HID];
                const float cn = fv * sc[l][unb][uj] + iv * gv;
                const float hn = ov * tanh_fast(cn);
                sc[l][unb][uj] = cn;
                sh[l][unb][uj] = hn;
            }
            __syncthreads();
        }
        if (!enc) {
            const int td = t - SEQLEN;
            if (tid < NB) {
                float s = fcb[0];
                #pragma unroll
                for (int j = 0; j < HID; j += 4) {
                    const float4 wv = *(const float4*)&fcW[j];
                    const float4 hv = *(const float4*)&sh[LAYERS - 1][tid][j];
                    s += wv.x * hv.x + wv.y * hv.y + wv.z * hv.z + wv.w * hv.w;
                }
                out[(size_t)(b0 + tid) * PREDLEN + td] = s;
                sx[tid][0] = s;
            } else if (tid >= 64 && tid < 64 + NB * 3) {
                const int qd = tid - 64;
                const int nb = qd / 3, k = qd % 3;
                sx[nb][k + 1] = ff[((size_t)(b0 + nb) * PREDLEN + td) * 3 + k];
            }
        }
    }
}

extern "C" void kernel_launch(void* const* d_in, const int* in_sizes, int n_in,
                              void* d_out, int out_size, void* d_ws, size_t ws_size,
                              hipStream_t stream) {
    const float* x    = (const float*)d_in[0];
    const float* ff   = (const float*)d_in[1];
    const float* eW0  = (const float*)d_in[2];
    const float* eWih = (const float*)d_in[3];
    const float* eWhh = (const float*)d_in[4];
    const float* ebih = (const float*)d_in[5];
    const float* ebhh = (const float*)d_in[6];
    const float* dW0  = (const float*)d_in[7];
    const float* dWih = (const float*)d_in[8];
    const float* dWhh = (const float*)d_in[9];
    const float* dbih = (const float*)d_in[10];
    const float* dbhh = (const float*)d_in[11];
    const float* fcW  = (const float*)d_in[12];
    const float* fcb  = (const float*)d_in[13];

    if (ws_size >= WS_NEED) {
        prep_pack<<<(NPREP + 255) / 256, 256, 0, stream>>>(
            eW0, eWih, eWhh, ebih, ebhh, dW0, dWih, dWhh, dbih, dbhh, (float*)d_ws);
        lstm_main<<<BATCH / NB, NTHR, 0, stream>>>(
            x, ff, fcW, fcb, (const float*)d_ws, (float*)d_out);
    } else {
        lstm_fb<<<BATCH / NB, 640, 0, stream>>>(
            x, ff, eW0, eWih, eWhh, ebih, ebhh,
            dW0, dWih, dWhh, dbih, dbhh, fcW, fcb, (float*)d_out);
    }
}

// Round 11
// 5483.678 us; speedup vs baseline: 1.2798x; 1.2798x over previous
//
#include <hip/hip_runtime.h>
#include <math.h>

// Seq2seq LSTM: 5-layer stack, HID=80, 336 enc + 48 dec steps, batch 512.
// R11: R9 (proven 5.09ms) + encoder inner loop rebuilt as A/B ping-pong with
//      prefetch distance 2 and NO register copies, keeping R9's coalesced SoA
//      weight layout (R10's j-contiguous repack un-coalesced the stream and
//      regressed). Layer-0 worker trimmed to 12 real chunks (was 20 w/ zeros).
#define LAYERS  5
#define HID     80
#define GATES   320
#define INDIM   4
#define BATCH   512
#define SEQLEN  336
#define PREDLEN 48
#define TOT     (SEQLEN + PREDLEN)
#define NB      4
#define NTHR    800
#define NSUP    (SEQLEN + LAYERS - 1)   // 340 supersteps

// h-buffer strides: per-batch 96 (80 h + 4 x-slot + pad), per-layer 384
#define BSTR 96
#define LSTR 384
#define HTOT (LAYERS * LSTR)            // 1920 floats per parity buffer

// ws (float4 units): [enc 64000][dec 64000][enc bias 400][dec bias 400]
//  enc (R9 SoA): idx ((wl*20+i)*4 + j)*160 + lt    lt=m*2+mat, row=m+80j
//       l>0: mat0=Whh[l][row][4i], mat1=Wih[l-1][row][4i]
//       l=0: mat0: i<10 ? Whh0[row][4i] : 0
//            mat1: i<10 ? Whh0[row][40+4i] : (i==10 ? W0[row][0:4] : 0)
//  dec (R9 SoA): idx ((5l+i)*4 + j)*640 + tid      tid=(m,mat,kq), k0=kq*20+4i
#define NE4    64000
#define ND4    64000
#define OFF_D  NE4
#define OFF_BE (NE4 + ND4)
#define OFF_BD (OFF_BE + 400)
#define NWS4   (OFF_BD + 400)
#define WS_NEED ((size_t)NWS4 * 16)
#define NPREP  (NE4 + ND4 + 800)

__device__ __forceinline__ float sigm(float v) { return 1.0f / (1.0f + __expf(-v)); }
__device__ __forceinline__ float tanh_fast(float v) {
    return 1.0f - 2.0f / (1.0f + __expf(2.0f * v));
}
__device__ __forceinline__ float gate_act(float v, bool tg) {
    const float e = __expf(tg ? 2.0f * v : -v);
    const float r = 1.0f / (1.0f + e);
    return tg ? 1.0f - 2.0f * r : r;
}
__device__ __forceinline__ float rs4(float v0, float v1, float v2, float v3, int q) {
    float u = (q & 1) ? v1 : v0;
    float s = (q & 1) ? v0 : v1;
    u += __shfl_xor(s, 1);
    float u2 = (q & 1) ? v3 : v2;
    float s2 = (q & 1) ? v2 : v3;
    u2 += __shfl_xor(s2, 1);
    float k = (q & 2) ? u2 : u;
    float s3 = (q & 2) ? u : u2;
    k += __shfl_xor(s3, 2);
    return k;
}

// 16 float4-FMAs into a[4][4]
#define FMA16(W, H)                                                              \
    do {                                                                         \
        _Pragma("unroll")                                                        \
        for (int _j = 0; _j < 4; ++_j) {                                         \
            _Pragma("unroll")                                                    \
            for (int _b = 0; _b < 4; ++_b)                                       \
                a[_j][_b] += (W)[_j].x * (H)[_b].x + (W)[_j].y * (H)[_b].y       \
                           + (W)[_j].z * (H)[_b].z + (W)[_j].w * (H)[_b].w;      \
        }                                                                        \
    } while (0)

// ================= prep: pack weights/biases (R9 layout) =================
__global__ void prep_pack(const float* __restrict__ eW0,  const float* __restrict__ eWih,
                          const float* __restrict__ eWhh, const float* __restrict__ ebih,
                          const float* __restrict__ ebhh,
                          const float* __restrict__ dW0,  const float* __restrict__ dWih,
                          const float* __restrict__ dWhh, const float* __restrict__ dbih,
                          const float* __restrict__ dbhh, float* __restrict__ ws)
{
    const int gid = blockIdx.x * 256 + threadIdx.x;
    float4* w4 = (float4*)ws;
    if (gid < NE4) {                    // encoder wavefront layout
        const int lt = gid % 160;
        const int j  = (gid / 160) & 3;
        const int i  = (gid / 640) % 20;
        const int l  = gid / 12800;
        const int m = lt >> 1, mat = lt & 1;
        const int row = m + 80 * j;
        float4 v = make_float4(0.f, 0.f, 0.f, 0.f);
        if (l > 0) {
            v = mat ? *(const float4*)&eWih[((size_t)(l - 1) * GATES + row) * HID + 4 * i]
                    : *(const float4*)&eWhh[((size_t)l * GATES + row) * HID + 4 * i];
        } else if (!mat) {
            if (i < 10) v = *(const float4*)&eWhh[(size_t)row * HID + 4 * i];
        } else {
            if (i < 10)       v = *(const float4*)&eWhh[(size_t)row * HID + 40 + 4 * i];
            else if (i == 10) v = *(const float4*)&eW0[row * INDIM];
        }
        w4[gid] = v;
        return;
    }
    int g2 = gid - NE4;
    if (g2 < ND4) {                     // decoder R8 layout
        const int tid  = g2 % 640;
        const int j    = (g2 / 640) & 3;
        const int slot = (g2 / 2560) % 25;
        const int m = tid >> 3, mat = (tid >> 2) & 1, kq = tid & 3;
        const int row = m + 80 * j;
        const int l = slot / 5, i = slot % 5;
        const int k0 = kq * 20 + 4 * i;
        float4 v = make_float4(0.f, 0.f, 0.f, 0.f);
        if (l == 0) {
            if (!mat)                    v = *(const float4*)&dWhh[(size_t)row * HID + k0];
            else if (kq == 0 && i == 0)  v = *(const float4*)&dW0[row * INDIM];
        } else {
            v = mat ? *(const float4*)&dWih[((size_t)(l - 1) * GATES + row) * HID + k0]
                    : *(const float4*)&dWhh[((size_t)l * GATES + row) * HID + k0];
        }
        w4[OFF_D + g2] = v;
        return;
    }
    int g3 = g2 - ND4;
    if (g3 < 800) {                     // biases: [ctx][l][m] f4 over gates
        const int ctx = g3 / 400, r = g3 % 400;
        const int l = r / 80, m = r % 80;
        const float* bi = ctx ? dbih : ebih;
        const float* bh = ctx ? dbhh : ebhh;
        float4 v;
        v.x = bi[l * GATES + m]       + bh[l * GATES + m];
        v.y = bi[l * GATES + m + 80]  + bh[l * GATES + m + 80];
        v.z = bi[l * GATES + m + 160] + bh[l * GATES + m + 160];
        v.w = bi[l * GATES + m + 240] + bh[l * GATES + m + 240];
        w4[OFF_BE + g3] = v;
    }
}

// ================= main persistent kernel =================
__global__ __launch_bounds__(NTHR) void lstm_main(
    const float* __restrict__ x,   const float* __restrict__ ff,
    const float* __restrict__ fcW, const float* __restrict__ fcb,
    const float* __restrict__ ws,  float* __restrict__ out)
{
    __shared__ __align__(16) float hA[HTOT];     // parity-0 h (+x slots)
    __shared__ __align__(16) float hB[HTOT];     // parity-1 h
    __shared__ __align__(16) float cS[LAYERS * NB * HID];
    __shared__ __align__(16) float sx[NB][20];   // decoder input (zero-padded)

    const float4* w4  = (const float4*)ws;
    const float4* w4d = w4 + OFF_D;
    const float4* b4e = w4 + OFF_BE;
    const float4* b4d = w4 + OFF_BD;

    const int tid = threadIdx.x;
    const int b0  = blockIdx.x * NB;

    for (int i = tid; i < HTOT; i += NTHR) { hA[i] = 0.0f; hB[i] = 0.0f; }
    for (int i = tid; i < LAYERS * NB * HID; i += NTHR) cS[i] = 0.0f;
    if (tid < NB * 20) ((float*)sx)[tid] = 0.0f;
    if (tid < NB)      // prestage x(0) into hB x-slots (prv of superstep 0)
        *(float4*)&hB[tid * BSTR + 80] = *(const float4*)&x[((size_t)(b0 + tid) * SEQLEN) * INDIM];
    __syncthreads();

    // ---------------- encoder: wavefront supersteps ----------------
    const int wl   = tid / 160;          // layer worker
    const int lt   = tid % 160;
    const int em   = lt >> 1;            // unit
    const int emat = lt & 1;             // matrix half
    const int npair = (wl == 0) ? 5 : 9; // chunks = 2*npair+2 (l0: 12, else 20)

    #pragma unroll 1
    for (int s = 0; s < NSUP; ++s) {
        float* cur = (s & 1) ? hB : hA;
        float* prv = (s & 1) ? hA : hB;
        const int t = s - wl;

        if (tid < NB && s + 1 < SEQLEN)  // stage x(s+1) into cur x-slot
            *(float4*)&cur[tid * BSTR + 80] =
                *(const float4*)&x[((size_t)(b0 + tid) * SEQLEN + (s + 1)) * INDIM];

        if (t >= 0 && t < SEQLEN) {
            const float* hbase = emat ? (wl ? prv + (wl - 1) * LSTR : prv + 40)
                                      : prv + wl * LSTR;
            const float4* wp = w4 + (size_t)wl * 12800 + lt;

            // A/B ping-pong, prefetch distance 2, no copies
            float4 wA[4], wB[4], hA4[4], hB4[4];
            wA[0] = wp[0];    wA[1] = wp[160];  wA[2] = wp[320];  wA[3] = wp[480];
            wB[0] = wp[640];  wB[1] = wp[800];  wB[2] = wp[960];  wB[3] = wp[1120];
            hA4[0] = *(const float4*)(hbase + 0 * BSTR);
            hA4[1] = *(const float4*)(hbase + 1 * BSTR);
            hA4[2] = *(const float4*)(hbase + 2 * BSTR);
            hA4[3] = *(const float4*)(hbase + 3 * BSTR);
            hB4[0] = *(const float4*)(hbase + 0 * BSTR + 4);
            hB4[1] = *(const float4*)(hbase + 1 * BSTR + 4);
            hB4[2] = *(const float4*)(hbase + 2 * BSTR + 4);
            hB4[3] = *(const float4*)(hbase + 3 * BSTR + 4);

            float a[4][4];
            #pragma unroll
            for (int j = 0; j < 4; ++j)
                #pragma unroll
                for (int b = 0; b < 4; ++b) a[j][b] = 0.0f;

            #pragma unroll 1
            for (int ii = 0; ii < npair; ++ii) {
                const float4* w2 = wp + 1280;    // chunk 2ii+2
                const float4* w3 = wp + 1920;    // chunk 2ii+3
                const int ho = 8 * ii + 8;
                FMA16(wA, hA4);
                wA[0] = w2[0];   wA[1] = w2[160]; wA[2] = w2[320]; wA[3] = w2[480];
                hA4[0] = *(const float4*)(hbase + 0 * BSTR + ho);
                hA4[1] = *(const float4*)(hbase + 1 * BSTR + ho);
                hA4[2] = *(const float4*)(hbase + 2 * BSTR + ho);
                hA4[3] = *(const float4*)(hbase + 3 * BSTR + ho);
                FMA16(wB, hB4);
                wB[0] = w3[0];   wB[1] = w3[160]; wB[2] = w3[320]; wB[3] = w3[480];
                hB4[0] = *(const float4*)(hbase + 0 * BSTR + ho + 4);
                hB4[1] = *(const float4*)(hbase + 1 * BSTR + ho + 4);
                hB4[2] = *(const float4*)(hbase + 2 * BSTR + ho + 4);
                hB4[3] = *(const float4*)(hbase + 3 * BSTR + ho + 4);
                wp = w2;
            }
            FMA16(wA, hA4);                      // chunk 2*npair
            FMA16(wB, hB4);                      // chunk 2*npair+1

            // 2-lane fold: lane keeps batches {2*emat, 2*emat+1}
            float sA[4], sB[4];
            #pragma unroll
            for (int j = 0; j < 4; ++j) {
                float u0 = emat ? a[j][0] : a[j][2];
                float r0 = __shfl_xor(u0, 1);
                sA[j] = (emat ? a[j][2] : a[j][0]) + r0;
                float u1 = emat ? a[j][1] : a[j][3];
                float r1 = __shfl_xor(u1, 1);
                sB[j] = (emat ? a[j][3] : a[j][1]) + r1;
            }

            const float4 bv = b4e[wl * 80 + em];
            const int blo = 2 * emat;
            {   // batch blo
                const float gi = sigm(sA[0] + bv.x);
                const float gf = sigm(sA[1] + bv.y);
                const float gg = tanh_fast(sA[2] + bv.z);
                const float go = sigm(sA[3] + bv.w);
                const int ci = wl * 320 + blo * 80 + em;
                const float cn = gf * cS[ci] + gi * gg;
                cS[ci] = cn;
                cur[wl * LSTR + blo * BSTR + em] = go * tanh_fast(cn);
            }
            {   // batch blo+1
                const float gi = sigm(sB[0] + bv.x);
                const float gf = sigm(sB[1] + bv.y);
                const float gg = tanh_fast(sB[2] + bv.z);
                const float go = sigm(sB[3] + bv.w);
                const int ci = wl * 320 + (blo + 1) * 80 + em;
                const float cn = gf * cS[ci] + gi * gg;
                cS[ci] = cn;
                cur[wl * LSTR + (blo + 1) * BSTR + em] = go * tanh_fast(cn);
            }
        }
        __syncthreads();
    }

    // ---------------- transition: gather final h into hB; stage dec input ----
    for (int i = tid; i < 2 * LSTR; i += NTHR) {
        const int l = (i < LSTR) ? 1 : 3;
        const int off = i % LSTR;
        hB[l * LSTR + off] = hA[l * LSTR + off];
    }
    if (tid < NB * INDIM)
        sx[tid >> 2][tid & 3] =
            x[((size_t)(b0 + (tid >> 2)) * SEQLEN + (SEQLEN - 1)) * INDIM + (tid & 3)];
    __syncthreads();

    // ---------------- decoder: R8 mapping on 640 threads (R9 verbatim) -------
    const int dm   = tid >> 3;
    const int dmat = (tid >> 2) & 1;
    const int dkq  = tid & 3;

    #pragma unroll 1
    for (int t = SEQLEN; t < TOT; ++t) {
        float* cur = (t & 1) ? hB : hA;
        float* prv = (t & 1) ? hA : hB;

        #pragma unroll 1
        for (int l = 0; l < LAYERS; ++l) {
            if (tid < 640) {
                const float* hb0;
                int hstr;
                if (l == 0) {
                    if (dmat) { hb0 = &sx[0][0];        hstr = 20;   }
                    else      { hb0 = prv + dkq * 20;   hstr = BSTR; }
                } else {
                    hb0 = (dmat ? (cur + (l - 1) * LSTR) : (prv + l * LSTR)) + dkq * 20;
                    hstr = BSTR;
                }
                const float* hb1 = hb0 + hstr;
                const float* hb2 = hb1 + hstr;
                const float* hb3 = hb2 + hstr;

                const float4* wp = w4d + (size_t)(5 * l) * 2560 + tid;
                float4 wv[4];
                wv[0] = wp[0]; wv[1] = wp[640]; wv[2] = wp[1280]; wv[3] = wp[1920];

                float a[4][4];
                #pragma unroll
                for (int j = 0; j < 4; ++j)
                    #pragma unroll
                    for (int b = 0; b < 4; ++b) a[j][b] = 0.0f;

                #pragma unroll 1
                for (int i = 0; i < 4; ++i) {
                    const float4* np = wp + 2560;
                    float4 nv[4];
                    nv[0] = np[0]; nv[1] = np[640]; nv[2] = np[1280]; nv[3] = np[1920];
                    float4 hv[4];
                    hv[0] = *(const float4*)(hb0 + 4 * i);
                    hv[1] = *(const float4*)(hb1 + 4 * i);
                    hv[2] = *(const float4*)(hb2 + 4 * i);
                    hv[3] = *(const float4*)(hb3 + 4 * i);
                    FMA16(wv, hv);
                    #pragma unroll
                    for (int j = 0; j < 4; ++j) wv[j] = nv[j];
                    wp = np;
                }
                {   // tail i = 4
                    float4 hv[4];
                    hv[0] = *(const float4*)(hb0 + 16);
                    hv[1] = *(const float4*)(hb1 + 16);
                    hv[2] = *(const float4*)(hb2 + 16);
                    hv[3] = *(const float4*)(hb3 + 16);
                    FMA16(wv, hv);
                }

                float s[4];
                #pragma unroll
                for (int j = 0; j < 4; ++j)
                    s[j] = rs4(a[j][0], a[j][1], a[j][2], a[j][3], dkq);
                #pragma unroll
                for (int j = 0; j < 4; ++j)
                    s[j] += __shfl_xor(s[j], 4);

                const float4 bv = b4d[l * 80 + dm];
                float act0, act1;
                if (!dmat) { act0 = sigm(s[0] + bv.x);      act1 = sigm(s[1] + bv.y); }
                else       { act0 = tanh_fast(s[2] + bv.z); act1 = sigm(s[3] + bv.w); }
                const float o0 = __shfl_xor(act0, 4);
                const float o1 = __shfl_xor(act1, 4);
                const float gi = dmat ? o0 : act0;
                const float gf = dmat ? o1 : act1;
                const float gg = dmat ? act0 : o0;
                const float go = dmat ? act1 : o1;

                if (!dmat) {
                    const int ci = l * 320 + dkq * 80 + dm;
                    const float cn = gf * cS[ci] + gi * gg;
                    cS[ci] = cn;
                    cur[l * LSTR + dkq * BSTR + dm] = go * tanh_fast(cn);
                }
            }
            __syncthreads();
        }

        const int td = t - SEQLEN;
        if (tid < NB) {                 // pred + feedback
            float s = fcb[0];
            const float* hvp = cur + 4 * LSTR + tid * BSTR;
            #pragma unroll
            for (int jj = 0; jj < HID; jj += 4) {
                const float4 wv4 = *(const float4*)&fcW[jj];
                const float4 h4  = *(const float4*)&hvp[jj];
                s += wv4.x * h4.x + wv4.y * h4.y + wv4.z * h4.z + wv4.w * h4.w;
            }
            out[(size_t)(b0 + tid) * PREDLEN + td] = s;
            sx[tid][0] = s;
        } else if (tid >= 64 && tid < 64 + NB * 3) {
            const int qd = tid - 64;
            const int nb = qd / 3, k = qd % 3;
            sx[nb][k + 1] = ff[((size_t)(b0 + nb) * PREDLEN + td) * 3 + k];
        }
        __syncthreads();
    }
}

// ================= fallback (R5 kernel, proven) if ws too small =================
#define FQK 20
#define FCHUNK(WPTR, HPTR, I)                                                    \
    do {                                                                         \
        const float4 wA = *(const float4*)((WPTR) + 4 * (I));                    \
        const float4 wB = *(const float4*)((WPTR) + HID + 4 * (I));              \
        const float* _hb = (HPTR);                                               \
        const float4 h0 = *(const float4*)(_hb + 0 * HID + 4 * (I));             \
        const float4 h1 = *(const float4*)(_hb + 1 * HID + 4 * (I));             \
        const float4 h2 = *(const float4*)(_hb + 2 * HID + 4 * (I));             \
        const float4 h3 = *(const float4*)(_hb + 3 * HID + 4 * (I));             \
        a00 += wA.x * h0.x + wA.y * h0.y + wA.z * h0.z + wA.w * h0.w;            \
        a01 += wA.x * h1.x + wA.y * h1.y + wA.z * h1.z + wA.w * h1.w;            \
        a02 += wA.x * h2.x + wA.y * h2.y + wA.z * h2.z + wA.w * h2.w;            \
        a03 += wA.x * h3.x + wA.y * h3.y + wA.z * h3.z + wA.w * h3.w;            \
        a10 += wB.x * h0.x + wB.y * h0.y + wB.z * h0.z + wB.w * h0.w;            \
        a11 += wB.x * h1.x + wB.y * h1.y + wB.z * h1.z + wB.w * h1.w;            \
        a12 += wB.x * h2.x + wB.y * h2.y + wB.z * h2.z + wB.w * h2.w;            \
        a13 += wB.x * h3.x + wB.y * h3.y + wB.z * h3.z + wB.w * h3.w;            \
    } while (0)

__global__ __launch_bounds__(640) void lstm_fb(
    const float* __restrict__ x,    const float* __restrict__ ff,
    const float* __restrict__ eW0,  const float* __restrict__ eWih,
    const float* __restrict__ eWhh, const float* __restrict__ ebih,
    const float* __restrict__ ebhh,
    const float* __restrict__ dW0,  const float* __restrict__ dWih,
    const float* __restrict__ dWhh, const float* __restrict__ dbih,
    const float* __restrict__ dbhh,
    const float* __restrict__ fcW,  const float* __restrict__ fcb,
    float* __restrict__ out)
{
    __shared__ __align__(16) float sh[LAYERS][NB][HID];
    __shared__ __align__(16) float sc[LAYERS][NB][HID];
    __shared__ __align__(16) float sg[NB][GATES + 1];
    __shared__ __align__(16) float sx[NB][INDIM];

    const int tid = threadIdx.x;
    const int q   = tid & 3;
    const int mm  = tid >> 2;
    const int r0  = 2 * mm;
    const int b0  = blockIdx.x * NB;

    for (int i = tid; i < LAYERS * NB * HID; i += 640) {
        (&sh[0][0][0])[i] = 0.0f;
        (&sc[0][0][0])[i] = 0.0f;
    }
    const bool is_tg = (r0 >= 2 * HID) && (r0 < 3 * HID);
    const int  unb = tid / HID, uj = tid % HID;

    float bs[2][LAYERS][2];
    #pragma unroll
    for (int l = 0; l < LAYERS; ++l) {
        bs[0][l][0] = ebih[l * GATES + r0]     + ebhh[l * GATES + r0];
        bs[0][l][1] = ebih[l * GATES + r0 + 1] + ebhh[l * GATES + r0 + 1];
        bs[1][l][0] = dbih[l * GATES + r0]     + dbhh[l * GATES + r0];
        bs[1][l][1] = dbih[l * GATES + r0 + 1] + dbhh[l * GATES + r0 + 1];
    }
    const float w0e0 = eW0[r0 * INDIM + q], w0e1 = eW0[(r0 + 1) * INDIM + q];
    const float w0d0 = dW0[r0 * INDIM + q], w0d1 = dW0[(r0 + 1) * INDIM + q];

    for (int t = 0; t < TOT; ++t) {
        const bool enc = (t < SEQLEN);
        const float* Wih = enc ? eWih : dWih;
        const float* Whh = enc ? eWhh : dWhh;
        if (enc && tid < NB * INDIM) {
            const int nb = tid / INDIM, k = tid % INDIM;
            sx[nb][k] = x[((size_t)(b0 + nb) * SEQLEN + t) * INDIM + k];
        }
        __syncthreads();
        #pragma unroll
        for (int l = 0; l < LAYERS; ++l) {
            float a00 = 0.f, a01 = 0.f, a02 = 0.f, a03 = 0.f;
            float a10 = 0.f, a11 = 0.f, a12 = 0.f, a13 = 0.f;
            {
                const float* wp = Whh + ((size_t)l * GATES + r0) * HID + q * FQK;
                const float* hp = &sh[l][0][q * FQK];
                #pragma unroll
                for (int i = 0; i < FQK / 4; ++i) FCHUNK(wp, hp, i);
            }
            if (l == 0) {
                const float wa = enc ? w0e0 : w0d0;
                const float wb = enc ? w0e1 : w0d1;
                a00 += wa * sx[0][q];  a01 += wa * sx[1][q];
                a02 += wa * sx[2][q];  a03 += wa * sx[3][q];
                a10 += wb * sx[0][q];  a11 += wb * sx[1][q];
                a12 += wb * sx[2][q];  a13 += wb * sx[3][q];
            } else {
                const float* wp = Wih + ((size_t)(l - 1) * GATES + r0) * HID + q * FQK;
                const float* hp = &sh[l - 1][0][q * FQK];
                #pragma unroll
                for (int i = 0; i < FQK / 4; ++i) FCHUNK(wp, hp, i);
            }
            const float s0 = rs4(a00, a01, a02, a03, q);
            const float s1 = rs4(a10, a11, a12, a13, q);
            const float bias0 = enc ? bs[0][l][0] : bs[1][l][0];
            const float bias1 = enc ? bs[0][l][1] : bs[1][l][1];
            sg[q][r0]     = gate_act(s0 + bias0, is_tg);
            sg[q][r0 + 1] = gate_act(s1 + bias1, is_tg);
            __syncthreads();
            if (tid < NB * HID) {
                const float iv = sg[unb][uj];
                const float fv = sg[unb][uj + HID];
                const float gv = sg[unb][uj + 2 * HID];
                const float ov = sg[unb][uj + 3 * HID];
                const float cn = fv * sc[l][unb][uj] + iv * gv;
                const float hn = ov * tanh_fast(cn);
                sc[l][unb][uj] = cn;
                sh[l][unb][uj] = hn;
            }
            __syncthreads();
        }
        if (!enc) {
            const int td = t - SEQLEN;
            if (tid < NB) {
                float s = fcb[0];
                #pragma unroll
                for (int j = 0; j < HID; j += 4) {
                    const float4 wv = *(const float4*)&fcW[j];
                    const float4 hv = *(const float4*)&sh[LAYERS - 1][tid][j];
                    s += wv.x * hv.x + wv.y * hv.y + wv.z * hv.z + wv.w * hv.w;
                }
                out[(size_t)(b0 + tid) * PREDLEN + td] = s;
                sx[tid][0] = s;
            } else if (tid >= 64 && tid < 64 + NB * 3) {
                const int qd = tid - 64;
                const int nb = qd / 3, k = qd % 3;
                sx[nb][k + 1] = ff[((size_t)(b0 + nb) * PREDLEN + td) * 3 + k];
            }
        }
    }
}

extern "C" void kernel_launch(void* const* d_in, const int* in_sizes, int n_in,
                              void* d_out, int out_size, void* d_ws, size_t ws_size,
                              hipStream_t stream) {
    const float* x    = (const float*)d_in[0];
    const float* ff   = (const float*)d_in[1];
    const float* eW0  = (const float*)d_in[2];
    const float* eWih = (const float*)d_in[3];
    const float* eWhh = (const float*)d_in[4];
    const float* ebih = (const float*)d_in[5];
    const float* ebhh = (const float*)d_in[6];
    const float* dW0  = (const float*)d_in[7];
    const float* dWih = (const float*)d_in[8];
    const float* dWhh = (const float*)d_in[9];
    const float* dbih = (const float*)d_in[10];
    const float* dbhh = (const float*)d_in[11];
    const float* fcW  = (const float*)d_in[12];
    const float* fcb  = (const float*)d_in[13];

    if (ws_size >= WS_NEED) {
        prep_pack<<<(NPREP + 255) / 256, 256, 0, stream>>>(
            eW0, eWih, eWhh, ebih, ebhh, dW0, dWih, dWhh, dbih, dbhh, (float*)d_ws);
        lstm_main<<<BATCH / NB, NTHR, 0, stream>>>(
            x, ff, fcW, fcb, (const float*)d_ws, (float*)d_out);
    } else {
        lstm_fb<<<BATCH / NB, 640, 0, stream>>>(
            x, ff, eW0, eWih, eWhh, ebih, ebhh,
            dW0, dWih, dWhh, dbih, dbhh, fcW, fcb, (float*)d_out);
    }
}

// Round 12
// 4095.156 us; speedup vs baseline: 1.7138x; 1.3391x over previous
//
#include <hip/hip_runtime.h>
#include <math.h>

// Seq2seq LSTM: 5-layer stack, HID=80, 336 enc + 48 dec steps, batch 512.
// R12: NB=2 per block, 256 blocks -> ALL 256 CUs active (was 128). Derived
//      counters normalize over all CUs: reported VALUBusy 33.6% == ~67% on
//      the active half => issue-bound regime; halving per-CU work is the
//      remaining lever (R8/R10/R11 scheduling changes were all null).
//      Encoder wavefront structure = R9 (proven); folds simplified for NB=2.
#define LAYERS  5
#define HID     80
#define GATES   320
#define INDIM   4
#define BATCH   512
#define SEQLEN  336
#define PREDLEN 48
#define TOT     (SEQLEN + PREDLEN)
#define NB      4            // fallback kernel's batch/block
#define ENB     2            // main kernel's batch/block
#define NTHR    800
#define NSUP    (SEQLEN + LAYERS - 1)   // 340 supersteps

// h-buffer strides: per-batch 96 (80 h + 4 x-slot + pad), per-layer 192
#define BSTR 96
#define LSTR (ENB * BSTR)        // 192
#define HTOT (LAYERS * LSTR)     // 960 floats per parity buffer
#define CSZ  (LAYERS * ENB * HID)// 800

// ws (float4): [enc 64000][dec 64000][bias_e 400][bias_d 400][w0dec 1280]
//  enc (R9 SoA, unchanged): idx ((wl*20+i)*4 + j)*160 + lt   lt=em*2+emat
//  dec (NEW):               idx ((l*10+i)*4 + j)*320 + lt    lt=dm*4+dmat*2+dkh
//       l>0: mat0=Whh[l][row][dkh*40+4i], mat1=Wih[l-1][row][...]
//       l=0: mat0=Whh0[row][dkh*40+4i],   mat1=0 (W0 via w0dec table)
//  w0dec: f4[j*320 + lt] = dW0 row (dm+80j)
#define NE4     64000
#define ND4     64000
#define OFF_D   NE4
#define OFF_BE  (NE4 + ND4)      // 128000
#define OFF_BD  (OFF_BE + 400)   // 128400
#define OFF_W0D (OFF_BD + 400)   // 128800
#define NWS4    (OFF_W0D + 1280) // 130080
#define WS_NEED ((size_t)NWS4 * 16)
#define NPREP   NWS4

__device__ __forceinline__ float sigm(float v) { return 1.0f / (1.0f + __expf(-v)); }
__device__ __forceinline__ float tanh_fast(float v) {
    return 1.0f - 2.0f / (1.0f + __expf(2.0f * v));
}
__device__ __forceinline__ float gate_act(float v, bool tg) {
    const float e = __expf(tg ? 2.0f * v : -v);
    const float r = 1.0f / (1.0f + e);
    return tg ? 1.0f - 2.0f * r : r;
}
__device__ __forceinline__ float rs4(float v0, float v1, float v2, float v3, int q) {
    float u = (q & 1) ? v1 : v0;
    float s = (q & 1) ? v0 : v1;
    u += __shfl_xor(s, 1);
    float u2 = (q & 1) ? v3 : v2;
    float s2 = (q & 1) ? v2 : v3;
    u2 += __shfl_xor(s2, 1);
    float k = (q & 2) ? u2 : u;
    float s3 = (q & 2) ? u : u2;
    k += __shfl_xor(s3, 2);
    return k;
}

// 8 float4-FMAs into a[4][2]
#define FMA8(W, H)                                                               \
    do {                                                                         \
        _Pragma("unroll")                                                        \
        for (int _j = 0; _j < 4; ++_j) {                                         \
            _Pragma("unroll")                                                    \
            for (int _b = 0; _b < 2; ++_b)                                       \
                a[_j][_b] += (W)[_j].x * (H)[_b].x + (W)[_j].y * (H)[_b].y       \
                           + (W)[_j].z * (H)[_b].z + (W)[_j].w * (H)[_b].w;      \
        }                                                                        \
    } while (0)

// ================= prep: pack weights/biases =================
__global__ void prep_pack(const float* __restrict__ eW0,  const float* __restrict__ eWih,
                          const float* __restrict__ eWhh, const float* __restrict__ ebih,
                          const float* __restrict__ ebhh,
                          const float* __restrict__ dW0,  const float* __restrict__ dWih,
                          const float* __restrict__ dWhh, const float* __restrict__ dbih,
                          const float* __restrict__ dbhh, float* __restrict__ ws)
{
    const int gid = blockIdx.x * 256 + threadIdx.x;
    float4* w4 = (float4*)ws;
    if (gid < NE4) {                    // encoder wavefront layout (R9)
        const int lt = gid % 160;
        const int j  = (gid / 160) & 3;
        const int i  = (gid / 640) % 20;
        const int l  = gid / 12800;
        const int m = lt >> 1, mat = lt & 1;
        const int row = m + 80 * j;
        float4 v = make_float4(0.f, 0.f, 0.f, 0.f);
        if (l > 0) {
            v = mat ? *(const float4*)&eWih[((size_t)(l - 1) * GATES + row) * HID + 4 * i]
                    : *(const float4*)&eWhh[((size_t)l * GATES + row) * HID + 4 * i];
        } else if (!mat) {
            if (i < 10) v = *(const float4*)&eWhh[(size_t)row * HID + 4 * i];
        } else {
            if (i < 10)       v = *(const float4*)&eWhh[(size_t)row * HID + 40 + 4 * i];
            else if (i == 10) v = *(const float4*)&eW0[row * INDIM];
        }
        w4[gid] = v;
        return;
    }
    int g2 = gid - NE4;
    if (g2 < ND4) {                     // decoder k-half layout
        const int lt = g2 % 320;
        const int j  = (g2 / 320) & 3;
        const int i  = (g2 / 1280) % 10;
        const int l  = g2 / 12800;
        const int dm = lt >> 2, dmat = (lt >> 1) & 1, dkh = lt & 1;
        const int row = dm + 80 * j;
        const int k0  = dkh * 40 + 4 * i;
        float4 v = make_float4(0.f, 0.f, 0.f, 0.f);
        if (l == 0) {
            if (!dmat) v = *(const float4*)&dWhh[(size_t)row * HID + k0];
        } else {
            v = dmat ? *(const float4*)&dWih[((size_t)(l - 1) * GATES + row) * HID + k0]
                     : *(const float4*)&dWhh[((size_t)l * GATES + row) * HID + k0];
        }
        w4[OFF_D + g2] = v;
        return;
    }
    int g3 = g2 - ND4;
    if (g3 < 800) {                     // biases: [ctx][l][m] f4 over gates
        const int ctx = g3 / 400, r = g3 % 400;
        const int l = r / 80, m = r % 80;
        const float* bi = ctx ? dbih : ebih;
        const float* bh = ctx ? dbhh : ebhh;
        float4 v;
        v.x = bi[l * GATES + m]       + bh[l * GATES + m];
        v.y = bi[l * GATES + m + 80]  + bh[l * GATES + m + 80];
        v.z = bi[l * GATES + m + 160] + bh[l * GATES + m + 160];
        v.w = bi[l * GATES + m + 240] + bh[l * GATES + m + 240];
        w4[OFF_BE + g3] = v;
        return;
    }
    int g4 = g3 - 800;
    if (g4 < 1280) {                    // decoder W0 rows
        const int lt = g4 % 320, j = g4 / 320;
        const int dm = lt >> 2;
        w4[OFF_W0D + g4] = *(const float4*)&dW0[(dm + 80 * j) * INDIM];
    }
}

// ================= main persistent kernel =================
__global__ __launch_bounds__(NTHR) void lstm_main(
    const float* __restrict__ x,   const float* __restrict__ ff,
    const float* __restrict__ fcW, const float* __restrict__ fcb,
    const float* __restrict__ ws,  float* __restrict__ out)
{
    __shared__ __align__(16) float hA[HTOT];     // parity-0 h (+x slots)
    __shared__ __align__(16) float hB[HTOT];     // parity-1 h
    __shared__ __align__(16) float cS[CSZ];
    __shared__ __align__(16) float sx[ENB][4];   // decoder input

    const float4* w4  = (const float4*)ws;
    const float4* w4d = w4 + OFF_D;
    const float4* b4e = w4 + OFF_BE;
    const float4* b4d = w4 + OFF_BD;
    const float4* w0d = w4 + OFF_W0D;

    const int tid = threadIdx.x;
    const int b0  = blockIdx.x * ENB;

    for (int i = tid; i < HTOT; i += NTHR) { hA[i] = 0.0f; hB[i] = 0.0f; }
    for (int i = tid; i < CSZ; i += NTHR) cS[i] = 0.0f;
    if (tid < ENB)     // prestage x(0) into hB x-slots (prv of superstep 0)
        *(float4*)&hB[tid * BSTR + 80] = *(const float4*)&x[((size_t)(b0 + tid) * SEQLEN) * INDIM];
    __syncthreads();

    // ---------------- encoder: wavefront supersteps ----------------
    const int wl   = tid / 160;          // layer worker
    const int lt   = tid % 160;
    const int em   = lt >> 1;            // unit
    const int emat = lt & 1;             // matrix half

    #pragma unroll 1
    for (int s = 0; s < NSUP; ++s) {
        float* cur = (s & 1) ? hB : hA;
        float* prv = (s & 1) ? hA : hB;
        const int t = s - wl;

        if (tid < ENB && s + 1 < SEQLEN)  // stage x(s+1) into cur x-slot
            *(float4*)&cur[tid * BSTR + 80] =
                *(const float4*)&x[((size_t)(b0 + tid) * SEQLEN + (s + 1)) * INDIM];

        if (t >= 0 && t < SEQLEN) {
            const float* hbase = emat ? (wl ? prv + (wl - 1) * LSTR : prv + 40)
                                      : prv + wl * LSTR;
            const float4* wp = w4 + (size_t)wl * 12800 + lt;
            float4 wv[4];
            wv[0] = wp[0]; wv[1] = wp[160]; wv[2] = wp[320]; wv[3] = wp[480];

            float a[4][2];
            #pragma unroll
            for (int j = 0; j < 4; ++j) { a[j][0] = 0.0f; a[j][1] = 0.0f; }

            #pragma unroll 1
            for (int i = 0; i < 19; ++i) {
                const float4* np = wp + 640;       // depth-1 prefetch (in-bounds)
                float4 nv[4];
                nv[0] = np[0]; nv[1] = np[160]; nv[2] = np[320]; nv[3] = np[480];
                float4 hv[2];
                hv[0] = *(const float4*)(hbase + 4 * i);
                hv[1] = *(const float4*)(hbase + BSTR + 4 * i);
                FMA8(wv, hv);
                #pragma unroll
                for (int j = 0; j < 4; ++j) wv[j] = nv[j];
                wp = np;
            }
            {                                       // tail i = 19
                float4 hv[2];
                hv[0] = *(const float4*)(hbase + 76);
                hv[1] = *(const float4*)(hbase + BSTR + 76);
                FMA8(wv, hv);
            }

            // mat fold: lane keeps batch emat
            float sA[4];
            #pragma unroll
            for (int j = 0; j < 4; ++j)
                sA[j] = a[j][emat] + __shfl_xor(a[j][emat ^ 1], 1);

            const float4 bv = b4e[wl * 80 + em];
            const float gi = sigm(sA[0] + bv.x);
            const float gf = sigm(sA[1] + bv.y);
            const float gg = tanh_fast(sA[2] + bv.z);
            const float go = sigm(sA[3] + bv.w);
            const int ci = wl * (ENB * HID) + emat * HID + em;
            const float cn = gf * cS[ci] + gi * gg;
            cS[ci] = cn;
            cur[wl * LSTR + emat * BSTR + em] = go * tanh_fast(cn);
        }
        __syncthreads();
    }

    // ---------------- transition: gather final h into hB; stage dec input ----
    // h_l(335) lives in buf[(335+l)&1]: layers 1,3 are in hA -> copy to hB.
    for (int i = tid; i < 2 * LSTR; i += NTHR) {
        const int l = (i < LSTR) ? 1 : 3;
        const int off = i % LSTR;
        hB[l * LSTR + off] = hA[l * LSTR + off];
    }
    if (tid < ENB * INDIM)
        sx[tid >> 2][tid & 3] =
            x[((size_t)(b0 + (tid >> 2)) * SEQLEN + (SEQLEN - 1)) * INDIM + (tid & 3)];
    __syncthreads();

    // ---------------- decoder: 320 threads (unit x mat x k-half) ----------
    const int dm   = tid >> 2;
    const int dmat = (tid >> 1) & 1;
    const int dkh  = tid & 1;

    #pragma unroll 1
    for (int t = SEQLEN; t < TOT; ++t) {
        float* cur = (t & 1) ? hB : hA;
        float* prv = (t & 1) ? hA : hB;

        #pragma unroll 1
        for (int l = 0; l < LAYERS; ++l) {
            if (tid < 320) {
                float a[4][2];
                #pragma unroll
                for (int j = 0; j < 4; ++j) { a[j][0] = 0.0f; a[j][1] = 0.0f; }

                if (l == 0 && dmat) {
                    if (dkh == 0) {        // W0 . x (both batches), once per quartet
                        const float4 xv0 = *(const float4*)&sx[0][0];
                        const float4 xv1 = *(const float4*)&sx[1][0];
                        #pragma unroll
                        for (int j = 0; j < 4; ++j) {
                            const float4 w0 = w0d[j * 320 + tid];
                            a[j][0] += w0.x * xv0.x + w0.y * xv0.y + w0.z * xv0.z + w0.w * xv0.w;
                            a[j][1] += w0.x * xv1.x + w0.y * xv1.y + w0.z * xv1.z + w0.w * xv1.w;
                        }
                    }
                } else {
                    const float* hb = (dmat ? cur + (l - 1) * LSTR : prv + l * LSTR)
                                      + dkh * 40;
                    const float4* wp = w4d + (size_t)l * 12800 + tid;
                    float4 wv[4];
                    wv[0] = wp[0]; wv[1] = wp[320]; wv[2] = wp[640]; wv[3] = wp[960];

                    #pragma unroll 1
                    for (int i = 0; i < 9; ++i) {
                        const float4* np = wp + 1280;
                        float4 nv[4];
                        nv[0] = np[0]; nv[1] = np[320]; nv[2] = np[640]; nv[3] = np[960];
                        float4 hv[2];
                        hv[0] = *(const float4*)(hb + 4 * i);
                        hv[1] = *(const float4*)(hb + BSTR + 4 * i);
                        FMA8(wv, hv);
                        #pragma unroll
                        for (int j = 0; j < 4; ++j) wv[j] = nv[j];
                        wp = np;
                    }
                    {   // tail i = 9
                        float4 hv[2];
                        hv[0] = *(const float4*)(hb + 36);
                        hv[1] = *(const float4*)(hb + BSTR + 36);
                        FMA8(wv, hv);
                    }
                }

                // fold: k-half (xor1, batch scatter) then mat (xor2)
                float s[4];
                #pragma unroll
                for (int j = 0; j < 4; ++j)
                    s[j] = a[j][dkh] + __shfl_xor(a[j][dkh ^ 1], 1);
                #pragma unroll
                for (int j = 0; j < 4; ++j)
                    s[j] += __shfl_xor(s[j], 2);

                const float4 bv = b4d[l * 80 + dm];
                float act0, act1;
                if (!dmat) { act0 = sigm(s[0] + bv.x);      act1 = sigm(s[1] + bv.y); }
                else       { act0 = tanh_fast(s[2] + bv.z); act1 = sigm(s[3] + bv.w); }
                const float o0 = __shfl_xor(act0, 2);
                const float o1 = __shfl_xor(act1, 2);
                if (!dmat) {
                    const float gi = act0, gf = act1, gg = o0, go = o1;
                    const int ci = l * (ENB * HID) + dkh * HID + dm;
                    const float cn = gf * cS[ci] + gi * gg;
                    cS[ci] = cn;
                    cur[l * LSTR + dkh * BSTR + dm] = go * tanh_fast(cn);
                }
            }
            __syncthreads();
        }

        const int td = t - SEQLEN;
        if (tid < ENB) {                // pred + feedback
            float s = fcb[0];
            const float* hvp = cur + 4 * LSTR + tid * BSTR;
            #pragma unroll
            for (int jj = 0; jj < HID; jj += 4) {
                const float4 wv4 = *(const float4*)&fcW[jj];
                const float4 h4  = *(const float4*)&hvp[jj];
                s += wv4.x * h4.x + wv4.y * h4.y + wv4.z * h4.z + wv4.w * h4.w;
            }
            out[(size_t)(b0 + tid) * PREDLEN + td] = s;
            sx[tid][0] = s;
        } else if (tid >= 64 && tid < 64 + ENB * 3) {
            const int qd = tid - 64;
            const int nb = qd / 3, k = qd % 3;
            sx[nb][k + 1] = ff[((size_t)(b0 + nb) * PREDLEN + td) * 3 + k];
        }
        __syncthreads();
    }
}

// ================= fallback (R5 kernel, proven) if ws too small =================
#define FQK 20
#define FCHUNK(WPTR, HPTR, I)                                                    \
    do {                                                                         \
        const float4 wA = *(const float4*)((WPTR) + 4 * (I));                    \
        const float4 wB = *(const float4*)((WPTR) + HID + 4 * (I));              \
        const float* _hb = (HPTR);                                               \
        const float4 h0 = *(const float4*)(_hb + 0 * HID + 4 * (I));             \
        const float4 h1 = *(const float4*)(_hb + 1 * HID + 4 * (I));             \
        const float4 h2 = *(const float4*)(_hb + 2 * HID + 4 * (I));             \
        const float4 h3 = *(const float4*)(_hb + 3 * HID + 4 * (I));             \
        a00 += wA.x * h0.x + wA.y * h0.y + wA.z * h0.z + wA.w * h0.w;            \
        a01 += wA.x * h1.x + wA.y * h1.y + wA.z * h1.z + wA.w * h1.w;            \
        a02 += wA.x * h2.x + wA.y * h2.y + wA.z * h2.z + wA.w * h2.w;            \
        a03 += wA.x * h3.x + wA.y * h3.y + wA.z * h3.z + wA.w * h3.w;            \
        a10 += wB.x * h0.x + wB.y * h0.y + wB.z * h0.z + wB.w * h0.w;            \
        a11 += wB.x * h1.x + wB.y * h1.y + wB.z * h1.z + wB.w * h1.w;            \
        a12 += wB.x * h2.x + wB.y * h2.y + wB.z * h2.z + wB.w * h2.w;            \
        a13 += wB.x * h3.x + wB.y * h3.y + wB.z * h3.z + wB.w * h3.w;            \
    } while (0)

__global__ __launch_bounds__(640) void lstm_fb(
    const float* __restrict__ x,    const float* __restrict__ ff,
    const float* __restrict__ eW0,  const float* __restrict__ eWih,
    const float* __restrict__ eWhh, const float* __restrict__ ebih,
    const float* __restrict__ ebhh,
    const float* __restrict__ dW0,  const float* __restrict__ dWih,
    const float* __restrict__ dWhh, const float* __restrict__ dbih,
    const float* __restrict__ dbhh,
    const float* __restrict__ fcW,  const float* __restrict__ fcb,
    float* __restrict__ out)
{
    __shared__ __align__(16) float sh[LAYERS][NB][HID];
    __shared__ __align__(16) float sc[LAYERS][NB][HID];
    __shared__ __align__(16) float sg[NB][GATES + 1];
    __shared__ __align__(16) float sx[NB][INDIM];

    const int tid = threadIdx.x;
    const int q   = tid & 3;
    const int mm  = tid >> 2;
    const int r0  = 2 * mm;
    const int b0  = blockIdx.x * NB;

    for (int i = tid; i < LAYERS * NB * HID; i += 640) {
        (&sh[0][0][0])[i] = 0.0f;
        (&sc[0][0][0])[i] = 0.0f;
    }
    const bool is_tg = (r0 >= 2 * HID) && (r0 < 3 * HID);
    const int  unb = tid / HID, uj = tid % HID;

    float bs[2][LAYERS][2];
    #pragma unroll
    for (int l = 0; l < LAYERS; ++l) {
        bs[0][l][0] = ebih[l * GATES + r0]     + ebhh[l * GATES + r0];
        bs[0][l][1] = ebih[l * GATES + r0 + 1] + ebhh[l * GATES + r0 + 1];
        bs[1][l][0] = dbih[l * GATES + r0]     + dbhh[l * GATES + r0];
        bs[1][l][1] = dbih[l * GATES + r0 + 1] + dbhh[l * GATES + r0 + 1];
    }
    const float w0e0 = eW0[r0 * INDIM + q], w0e1 = eW0[(r0 + 1) * INDIM + q];
    const float w0d0 = dW0[r0 * INDIM + q], w0d1 = dW0[(r0 + 1) * INDIM + q];

    for (int t = 0; t < TOT; ++t) {
        const bool enc = (t < SEQLEN);
        const float* Wih = enc ? eWih : dWih;
        const float* Whh = enc ? eWhh : dWhh;
        if (enc && tid < NB * INDIM) {
            const int nb = tid / INDIM, k = tid % INDIM;
            sx[nb][k] = x[((size_t)(b0 + nb) * SEQLEN + t) * INDIM + k];
        }
        __syncthreads();
        #pragma unroll
        for (int l = 0; l < LAYERS; ++l) {
            float a00 = 0.f, a01 = 0.f, a02 = 0.f, a03 = 0.f;
            float a10 = 0.f, a11 = 0.f, a12 = 0.f, a13 = 0.f;
            {
                const float* wp = Whh + ((size_t)l * GATES + r0) * HID + q * FQK;
                const float* hp = &sh[l][0][q * FQK];
                #pragma unroll
                for (int i = 0; i < FQK / 4; ++i) FCHUNK(wp, hp, i);
            }
            if (l == 0) {
                const float wa = enc ? w0e0 : w0d0;
                const float wb = enc ? w0e1 : w0d1;
                a00 += wa * sx[0][q];  a01 += wa * sx[1][q];
                a02 += wa * sx[2][q];  a03 += wa * sx[3][q];
                a10 += wb * sx[0][q];  a11 += wb * sx[1][q];
                a12 += wb * sx[2][q];  a13 += wb * sx[3][q];
            } else {
                const float* wp = Wih + ((size_t)(l - 1) * GATES + r0) * HID + q * FQK;
                const float* hp = &sh[l - 1][0][q * FQK];
                #pragma unroll
                for (int i = 0; i < FQK / 4; ++i) FCHUNK(wp, hp, i);
            }
            const float s0 = rs4(a00, a01, a02, a03, q);
            const float s1 = rs4(a10, a11, a12, a13, q);
            const float bias0 = enc ? bs[0][l][0] : bs[1][l][0];
            const float bias1 = enc ? bs[0][l][1] : bs[1][l][1];
            sg[q][r0]     = gate_act(s0 + bias0, is_tg);
            sg[q][r0 + 1] = gate_act(s1 + bias1, is_tg);
            __syncthreads();
            if (tid < NB * HID) {
                const float iv = sg[unb][uj];
                const float fv = sg[unb][uj + HID];
                const float gv = sg[unb][uj + 2 * HID];
                const float ov = sg[unb][uj + 3 * HID];
                const float cn = fv * sc[l][unb][uj] + iv * gv;
                const float hn = ov * tanh_fast(cn);
                sc[l][unb][uj] = cn;
                sh[l][unb][uj] = hn;
            }
            __syncthreads();
        }
        if (!enc) {
            const int td = t - SEQLEN;
            if (tid < NB) {
                float s = fcb[0];
                #pragma unroll
                for (int j = 0; j < HID; j += 4) {
                    const float4 wv = *(const float4*)&fcW[j];
                    const float4 hv = *(const float4*)&sh[LAYERS - 1][tid][j];
                    s += wv.x * hv.x + wv.y * hv.y + wv.z * hv.z + wv.w * hv.w;
                }
                out[(size_t)(b0 + tid) * PREDLEN + td] = s;
                sx[tid][0] = s;
            } else if (tid >= 64 && tid < 64 + NB * 3) {
                const int qd = tid - 64;
                const int nb = qd / 3, k = qd % 3;
                sx[nb][k + 1] = ff[((size_t)(b0 + nb) * PREDLEN + td) * 3 + k];
            }
        }
    }
}

extern "C" void kernel_launch(void* const* d_in, const int* in_sizes, int n_in,
                              void* d_out, int out_size, void* d_ws, size_t ws_size,
                              hipStream_t stream) {
    const float* x    = (const float*)d_in[0];
    const float* ff   = (const float*)d_in[1];
    const float* eW0  = (const float*)d_in[2];
    const float* eWih = (const float*)d_in[3];
    const float* eWhh = (const float*)d_in[4];
    const float* ebih = (const float*)d_in[5];
    const float* ebhh = (const float*)d_in[6];
    const float* dW0  = (const float*)d_in[7];
    const float* dWih = (const float*)d_in[8];
    const float* dWhh = (const float*)d_in[9];
    const float* dbih = (const float*)d_in[10];
    const float* dbhh = (const float*)d_in[11];
    const float* fcW  = (const float*)d_in[12];
    const float* fcb  = (const float*)d_in[13];

    if (ws_size >= WS_NEED) {
        prep_pack<<<(NPREP + 255) / 256, 256, 0, stream>>>(
            eW0, eWih, eWhh, ebih, ebhh, dW0, dWih, dWhh, dbih, dbhh, (float*)d_ws);
        lstm_main<<<BATCH / ENB, NTHR, 0, stream>>>(
            x, ff, fcW, fcb, (const float*)d_ws, (float*)d_out);
    } else {
        lstm_fb<<<BATCH / NB, 640, 0, stream>>>(
            x, ff, eW0, eWih, eWhh, ebih, ebhh,
            dW0, dWih, dWhh, dbih, dbhh, fcW, fcb, (float*)d_out);
    }
}